// Round 4
// baseline (155.841 us; speedup 1.0000x reference)
//
#include <hip/hip_runtime.h>
#include <hip/hip_bf16.h>

typedef __attribute__((ext_vector_type(8))) short bf16x8;
typedef __attribute__((ext_vector_type(4))) float f32x4;

__device__ __forceinline__ float sigmoidf_(float v) {
    return 1.0f / (1.0f + __expf(-v));
}
__device__ __forceinline__ short f2bf(float f) {
    union { __hip_bfloat16 h; short s; } cv;
    cv.h = __float2bfloat16(f);
    return cv.s;
}
__device__ __forceinline__ float bf2f(short s) {
    union { float f; unsigned u; } cv;
    cv.u = ((unsigned)(unsigned short)s) << 16;
    return cv.f;
}

// ---------------------------------------------------------------------------
// Kernel 0: conversions, all coalesced.
//  b in [0,256)  : xb[1024][512] = bf16(x)
//  b in [256,320): transpose pp_w1 -> Wt rows 0..511
//  b in [320,384): transpose cd_w1 -> Wt rows 512..1023 (U|V)
//  b in [384,392): transpose cd_w2 -> w2t [128][256]
//  b == 392      : pack hw[10][512]
// ---------------------------------------------------------------------------
__global__ __launch_bounds__(256) void convert_kernel(
    const float* __restrict__ x, const float* __restrict__ pp_w1,
    const float* __restrict__ cd_w1, const float* __restrict__ cd_w2,
    const float* __restrict__ pp_w2, const float* __restrict__ vel_w,
    const float* __restrict__ frc_w,
    __hip_bfloat16* __restrict__ xb, __hip_bfloat16* __restrict__ Wt,
    __hip_bfloat16* __restrict__ w2t, float* __restrict__ hw)
{
    __shared__ float ts[64][65];
    const int b = blockIdx.x, t = threadIdx.x;

    if (b < 256) {  // xb cast
        int base = b * 2048 + t * 8;
        float4 a = *(const float4*)(x + base);
        float4 c = *(const float4*)(x + base + 4);
        bf16x8 o;
        o[0] = f2bf(a.x); o[1] = f2bf(a.y); o[2] = f2bf(a.z); o[3] = f2bf(a.w);
        o[4] = f2bf(c.x); o[5] = f2bf(c.y); o[6] = f2bf(c.z); o[7] = f2bf(c.w);
        *(bf16x8*)(xb + base) = o;
        return;
    }
    if (b == 392) {  // hw pack
        for (int e = t; e < 5120; e += 256) {
            int h = e >> 9, k = e & 511;
            float v = (h < 4) ? pp_w2[k * 128 + h]
                    : (h < 7) ? vel_w[k * 3 + (h - 4)]
                              : frc_w[k * 3 + (h - 7)];
            hw[e] = v;
        }
        return;
    }

    const float* src; int ss, k0, n0, region;
    if (b < 320)      { int i = b - 256; src = pp_w1; ss = 512; k0 = (i >> 3) * 64; n0 = (i & 7) * 64; region = 0; }
    else if (b < 384) { int i = b - 320; src = cd_w1; ss = 256; k0 = (i >> 2) * 64; n0 = (i & 3) * 64; region = 1; }
    else              { int i = b - 384; src = cd_w2; ss = 128; k0 = (i >> 1) * 64; n0 = (i & 1) * 64; region = 2; }

    #pragma unroll
    for (int i = 0; i < 4; ++i) {
        int r = (t >> 4) + i * 16, c4 = (t & 15) * 4;
        *(float4*)&ts[r][c4] = *(const float4*)(src + (k0 + r) * ss + n0 + c4);
    }
    __syncthreads();
    #pragma unroll
    for (int i = 0; i < 4; ++i) {
        int nOut = (t >> 4) + i * 16, kc = (t & 15) * 4;
        ushort4 o;
        o.x = (unsigned short)f2bf(ts[kc + 0][nOut]);
        o.y = (unsigned short)f2bf(ts[kc + 1][nOut]);
        o.z = (unsigned short)f2bf(ts[kc + 2][nOut]);
        o.w = (unsigned short)f2bf(ts[kc + 3][nOut]);
        int gn = n0 + nOut, gk = k0 + kc;
        if (region == 0)      *(ushort4*)(Wt + gn * 512 + gk) = o;
        else if (region == 1) {
            int row = (gk < 512) ? (512 + gn) : (768 + gn);
            *(ushort4*)(Wt + row * 512 + (gk & 511)) = o;
        } else                *(ushort4*)(w2t + gn * 256 + gk) = o;
    }
}

// ---------------------------------------------------------------------------
// Kernel 1: MFMA GEMM C[1024][1024] = xb @ Wt^T. 16x32 per wave, grid (8,64)
// -> 2048 waves (2/SIMD) for latency hiding. Fragments straight from L2.
// ---------------------------------------------------------------------------
__global__ __launch_bounds__(256) void gemm_kernel(
    const __hip_bfloat16* __restrict__ xb, const __hip_bfloat16* __restrict__ Wt,
    const float* __restrict__ pp_b1, const float* __restrict__ cd_b1,
    __hip_bfloat16* __restrict__ hidg, float* __restrict__ Ug,
    float* __restrict__ Vg)
{
    const int t = threadIdx.x;
    const int wave = t >> 6, lane = t & 63;
    const int l = lane & 15, q = lane >> 4;
    const int m0 = blockIdx.y * 16;
    const int n0 = blockIdx.x * 128 + wave * 32;

    const __hip_bfloat16* ap  = xb + (m0 + l) * 512 + q * 8;
    const __hip_bfloat16* b0p = Wt + (n0 + l) * 512 + q * 8;
    const __hip_bfloat16* b1p = b0p + 16 * 512;

    f32x4 acc0 = {}, acc1 = {};
    #pragma unroll
    for (int ks = 0; ks < 16; ++ks) {
        bf16x8 a  = *(const bf16x8*)(ap  + ks * 32);
        bf16x8 b0 = *(const bf16x8*)(b0p + ks * 32);
        bf16x8 b1 = *(const bf16x8*)(b1p + ks * 32);
        acc0 = __builtin_amdgcn_mfma_f32_16x16x32_bf16(a, b0, acc0, 0, 0, 0);
        acc1 = __builtin_amdgcn_mfma_f32_16x16x32_bf16(a, b1, acc1, 0, 0, 0);
    }

    // C/D layout: col = l, row = q*4 + r
    const int c0 = n0 + l, c1 = n0 + 16 + l;
    if (n0 < 512) {
        float b0v = pp_b1[c0], b1v = pp_b1[c1];
        #pragma unroll
        for (int r = 0; r < 4; ++r) {
            int rg = m0 + q * 4 + r;
            hidg[rg * 512 + c0] = __float2bfloat16(fmaxf(acc0[r] + b0v, 0.f));
            hidg[rg * 512 + c1] = __float2bfloat16(fmaxf(acc1[r] + b1v, 0.f));
        }
    } else if (n0 < 768) {
        float b0v = cd_b1[c0 - 512], b1v = cd_b1[c1 - 512];
        #pragma unroll
        for (int r = 0; r < 4; ++r) {
            int rg = m0 + q * 4 + r;
            Ug[rg * 256 + (c0 - 512)] = acc0[r] + b0v;
            Ug[rg * 256 + (c1 - 512)] = acc1[r] + b1v;
        }
    } else {
        #pragma unroll
        for (int r = 0; r < 4; ++r) {
            int rg = m0 + q * 4 + r;
            Vg[rg * 256 + (c0 - 768)] = acc0[r];
            Vg[rg * 256 + (c1 - 768)] = acc1[r];
        }
    }
}

// ---------------------------------------------------------------------------
// Kernel 2: heads. One wave per row; 10 coalesced shuffle-reduce dots.
// ---------------------------------------------------------------------------
__global__ __launch_bounds__(256) void heads_kernel(
    const float* __restrict__ x, const __hip_bfloat16* __restrict__ hidg,
    const float* __restrict__ hw, const float* __restrict__ pp_b2,
    const float* __restrict__ vel_b, const float* __restrict__ frc_b,
    float* __restrict__ out)
{
    const int t = threadIdx.x, wave = t >> 6, lane = t & 63;
    const int row = blockIdx.x * 4 + wave;

    const float4* xr = (const float4*)(x + row * 512);
    float4 xa = xr[lane * 2], xc = xr[lane * 2 + 1];
    bf16x8 hb = *(const bf16x8*)(hidg + row * 512 + lane * 8);
    float hf[8];
    #pragma unroll
    for (int j = 0; j < 8; ++j) hf[j] = bf2f(hb[j]);

    #pragma unroll
    for (int h = 0; h < 10; ++h) {
        const float4* wr = (const float4*)(hw + h * 512);
        float4 wa = wr[lane * 2], wc = wr[lane * 2 + 1];
        float s;
        if (h < 4) {
            s = hf[0]*wa.x + hf[1]*wa.y + hf[2]*wa.z + hf[3]*wa.w
              + hf[4]*wc.x + hf[5]*wc.y + hf[6]*wc.z + hf[7]*wc.w;
        } else {
            s = xa.x*wa.x + xa.y*wa.y + xa.z*wa.z + xa.w*wa.w
              + xc.x*wc.x + xc.y*wc.y + xc.z*wc.z + xc.w*wc.w;
        }
        s += __shfl_xor(s, 1);  s += __shfl_xor(s, 2);
        s += __shfl_xor(s, 4);  s += __shfl_xor(s, 8);
        s += __shfl_xor(s, 16); s += __shfl_xor(s, 32);
        if (lane == 0) {
            if (h < 4) {
                float sg = sigmoidf_(s + pp_b2[h]);
                out[h * 1024 + row] = (h == 0) ? sg * 100.f : (h == 3) ? sg * 10.f : sg;
            } else if (h < 7) {
                out[4096 + row * 3 + (h - 4)] = s + vel_b[h - 4];
            } else {
                out[7168 + row * 3 + (h - 7)] = s + frc_b[h - 7];
            }
        }
    }
}

// ---------------------------------------------------------------------------
// Kernel 3: pair MLP. Triangular grid (528 x 4). h built ONCE into LDS bf16
// straight from global U/V (no Us/Vs staging). LDS 35 KB -> 4 blocks/CU.
// ---------------------------------------------------------------------------
__global__ __launch_bounds__(256) void pair_kernel(
    const float* __restrict__ Ug, const float* __restrict__ Vg,
    const __hip_bfloat16* __restrict__ w2t,  // [128][256] bf16
    const float* __restrict__ cd_b2, const float* __restrict__ cd_w3,
    const float* __restrict__ cd_b3, float* __restrict__ cm)
{
    const int b = blockIdx.y;
    const int tp = blockIdx.x;  // 0..527 -> (ti<=tj) of 32x32 tiles
    int ti = (int)((65.0f - sqrtf(4225.0f - 8.0f * (float)tp)) * 0.5f);
    while ((ti + 1) * (65 - (ti + 1)) / 2 <= tp) ++ti;
    while (ti * (65 - ti) / 2 > tp) --ti;
    const int tj = ti + (tp - ti * (65 - ti) / 2);

    __shared__ __align__(16) short hs[64][264];  // 33.8 KB
    __shared__ float ps[64][4];

    const int t = threadIdx.x;
    const int i0 = ti * 8, j0 = tj * 8;

    { // h[p][k] = relu(U[i0+pi][k] + V[j0+pj][k]); wave w builds k-quarter w
        const int p = t & 63, pi = p >> 3, pj = p & 7;
        const int kb = (t >> 6) * 64;
        const float* Up = Ug + (b * 256 + i0 + pi) * 256 + kb;
        const float* Vp = Vg + (b * 256 + j0 + pj) * 256 + kb;
        #pragma unroll
        for (int kk = 0; kk < 64; kk += 8) {
            float4 u0 = *(const float4*)(Up + kk);
            float4 u1 = *(const float4*)(Up + kk + 4);
            float4 v0 = *(const float4*)(Vp + kk);
            float4 v1 = *(const float4*)(Vp + kk + 4);
            bf16x8 pack;
            pack[0] = f2bf(fmaxf(u0.x + v0.x, 0.f));
            pack[1] = f2bf(fmaxf(u0.y + v0.y, 0.f));
            pack[2] = f2bf(fmaxf(u0.z + v0.z, 0.f));
            pack[3] = f2bf(fmaxf(u0.w + v0.w, 0.f));
            pack[4] = f2bf(fmaxf(u1.x + v1.x, 0.f));
            pack[5] = f2bf(fmaxf(u1.y + v1.y, 0.f));
            pack[6] = f2bf(fmaxf(u1.z + v1.z, 0.f));
            pack[7] = f2bf(fmaxf(u1.w + v1.w, 0.f));
            *(bf16x8*)&hs[p][kb + kk] = pack;
        }
    }
    __syncthreads();

    const int wave = t >> 6, lane = t & 63;
    const int l = lane & 15, q = lane >> 4;

    const __hip_bfloat16* wb0 = w2t + ((wave * 2 + 0) * 16 + l) * 256 + q * 8;
    const __hip_bfloat16* wb1 = wb0 + 16 * 256;

    f32x4 acc[4][2] = {};
    #pragma unroll
    for (int ks = 0; ks < 8; ++ks) {
        bf16x8 bfr0 = *(const bf16x8*)(wb0 + ks * 32);
        bf16x8 bfr1 = *(const bf16x8*)(wb1 + ks * 32);
        #pragma unroll
        for (int mt = 0; mt < 4; ++mt) {
            bf16x8 afr = *(const bf16x8*)&hs[mt * 16 + l][ks * 32 + q * 8];
            acc[mt][0] = __builtin_amdgcn_mfma_f32_16x16x32_bf16(afr, bfr0, acc[mt][0], 0, 0, 0);
            acc[mt][1] = __builtin_amdgcn_mfma_f32_16x16x32_bf16(afr, bfr1, acc[mt][1], 0, 0, 0);
        }
    }

    float b2v0 = cd_b2[(wave * 2 + 0) * 16 + l], b2v1 = cd_b2[(wave * 2 + 1) * 16 + l];
    float w3v0 = cd_w3[(wave * 2 + 0) * 16 + l], w3v1 = cd_w3[(wave * 2 + 1) * 16 + l];
    #pragma unroll
    for (int mt = 0; mt < 4; ++mt) {
        #pragma unroll
        for (int r = 0; r < 4; ++r) {
            // D layout: pair = mt*16 + q*4 + r, col = wave's channel l
            float g0 = fmaxf(acc[mt][0][r] + b2v0, 0.f);
            float g1 = fmaxf(acc[mt][1][r] + b2v1, 0.f);
            float s = g0 * w3v0 + g1 * w3v1;
            s += __shfl_xor(s, 1);
            s += __shfl_xor(s, 2);
            s += __shfl_xor(s, 4);
            s += __shfl_xor(s, 8);
            if (l == 0) ps[mt * 16 + q * 4 + r][wave] = s;
        }
    }
    __syncthreads();

    if (t < 64) {
        int p = t;
        float v = ps[p][0] + ps[p][1] + ps[p][2] + ps[p][3] + cd_b3[0];
        float prob = 1.0f / (1.0f + __expf(-v));
        int i = i0 + (p >> 3), j = j0 + (p & 7);
        float* base = cm + b * 65536;
        if (i < j) {
            base[i * 256 + j] = prob;
            base[j * 256 + i] = prob;
        } else if (i == j) {
            base[i * 256 + i] = 0.0f;
        }
    }
}

// ---------------------------------------------------------------------------
extern "C" void kernel_launch(void* const* d_in, const int* in_sizes, int n_in,
                              void* d_out, int out_size, void* d_ws, size_t ws_size,
                              hipStream_t stream) {
    const float* x     = (const float*)d_in[0];
    const float* pp_w1 = (const float*)d_in[1];
    const float* pp_b1 = (const float*)d_in[2];
    const float* pp_w2 = (const float*)d_in[3];
    const float* pp_b2 = (const float*)d_in[4];
    const float* cd_w1 = (const float*)d_in[5];
    const float* cd_b1 = (const float*)d_in[6];
    const float* cd_w2 = (const float*)d_in[7];
    const float* cd_b2 = (const float*)d_in[8];
    const float* cd_w3 = (const float*)d_in[9];
    const float* cd_b3 = (const float*)d_in[10];
    const float* vel_w = (const float*)d_in[11];
    const float* vel_b = (const float*)d_in[12];
    const float* frc_w = (const float*)d_in[13];
    const float* frc_b = (const float*)d_in[14];

    float* out = (float*)d_out;
    // ws: Ug 1MB | Vg 1MB | xb 1MB | Wt 1MB | hidg 1MB | w2t 64KB | hw 20KB
    float* Ug = (float*)d_ws;
    float* Vg = Ug + 262144;
    __hip_bfloat16* xb   = (__hip_bfloat16*)(Vg + 262144);
    __hip_bfloat16* Wt   = xb + 524288;
    __hip_bfloat16* hidg = Wt + 524288;
    __hip_bfloat16* w2t  = hidg + 524288;
    float* hw = (float*)(w2t + 32768);

    convert_kernel<<<dim3(393), dim3(256), 0, stream>>>(
        x, pp_w1, cd_w1, cd_w2, pp_w2, vel_w, frc_w, xb, Wt, w2t, hw);
    gemm_kernel<<<dim3(8, 64), dim3(256), 0, stream>>>(
        xb, Wt, pp_b1, cd_b1, hidg, Ug, Vg);
    heads_kernel<<<dim3(256), dim3(256), 0, stream>>>(
        x, hidg, hw, pp_b2, vel_b, frc_b, out);
    pair_kernel<<<dim3(528, 4), dim3(256), 0, stream>>>(
        Ug, Vg, w2t, cd_b2, cd_w3, cd_b3, out + 10240);
}

// Round 5
// 144.270 us; speedup vs baseline: 1.0802x; 1.0802x over previous
//
#include <hip/hip_runtime.h>
#include <hip/hip_bf16.h>

typedef __attribute__((ext_vector_type(8))) short bf16x8;
typedef __attribute__((ext_vector_type(4))) float f32x4;

__device__ __forceinline__ float sigmoidf_(float v) {
    return 1.0f / (1.0f + __expf(-v));
}
__device__ __forceinline__ short f2bf(float f) {
    union { __hip_bfloat16 h; short s; } cv;
    cv.h = __float2bfloat16(f);
    return cv.s;
}
__device__ __forceinline__ float bf2f(short s) {
    union { float f; unsigned u; } cv;
    cv.u = ((unsigned)(unsigned short)s) << 16;
    return cv.f;
}

// ---------------------------------------------------------------------------
// Kernel 0: conversions, all coalesced.
//  b in [0,256)  : xb[1024][512] = bf16(x)
//  b in [256,320): transpose pp_w1 -> Wt rows 0..511
//  b in [320,384): transpose cd_w1 -> Wt rows 512..1023 (U|V)
//  b in [384,392): transpose cd_w2 -> w2t [128][256]
//  b == 392      : pack hw[10][512]
// ---------------------------------------------------------------------------
__global__ __launch_bounds__(256) void convert_kernel(
    const float* __restrict__ x, const float* __restrict__ pp_w1,
    const float* __restrict__ cd_w1, const float* __restrict__ cd_w2,
    const float* __restrict__ pp_w2, const float* __restrict__ vel_w,
    const float* __restrict__ frc_w,
    __hip_bfloat16* __restrict__ xb, __hip_bfloat16* __restrict__ Wt,
    __hip_bfloat16* __restrict__ w2t, float* __restrict__ hw)
{
    __shared__ float ts[64][65];
    const int b = blockIdx.x, t = threadIdx.x;

    if (b < 256) {  // xb cast
        int base = b * 2048 + t * 8;
        float4 a = *(const float4*)(x + base);
        float4 c = *(const float4*)(x + base + 4);
        bf16x8 o;
        o[0] = f2bf(a.x); o[1] = f2bf(a.y); o[2] = f2bf(a.z); o[3] = f2bf(a.w);
        o[4] = f2bf(c.x); o[5] = f2bf(c.y); o[6] = f2bf(c.z); o[7] = f2bf(c.w);
        *(bf16x8*)(xb + base) = o;
        return;
    }
    if (b == 392) {  // hw pack
        for (int e = t; e < 5120; e += 256) {
            int h = e >> 9, k = e & 511;
            float v = (h < 4) ? pp_w2[k * 128 + h]
                    : (h < 7) ? vel_w[k * 3 + (h - 4)]
                              : frc_w[k * 3 + (h - 7)];
            hw[e] = v;
        }
        return;
    }

    const float* src; int ss, k0, n0, region;
    if (b < 320)      { int i = b - 256; src = pp_w1; ss = 512; k0 = (i >> 3) * 64; n0 = (i & 7) * 64; region = 0; }
    else if (b < 384) { int i = b - 320; src = cd_w1; ss = 256; k0 = (i >> 2) * 64; n0 = (i & 3) * 64; region = 1; }
    else              { int i = b - 384; src = cd_w2; ss = 128; k0 = (i >> 1) * 64; n0 = (i & 1) * 64; region = 2; }

    #pragma unroll
    for (int i = 0; i < 4; ++i) {
        int r = (t >> 4) + i * 16, c4 = (t & 15) * 4;
        *(float4*)&ts[r][c4] = *(const float4*)(src + (k0 + r) * ss + n0 + c4);
    }
    __syncthreads();
    #pragma unroll
    for (int i = 0; i < 4; ++i) {
        int nOut = (t >> 4) + i * 16, kc = (t & 15) * 4;
        ushort4 o;
        o.x = (unsigned short)f2bf(ts[kc + 0][nOut]);
        o.y = (unsigned short)f2bf(ts[kc + 1][nOut]);
        o.z = (unsigned short)f2bf(ts[kc + 2][nOut]);
        o.w = (unsigned short)f2bf(ts[kc + 3][nOut]);
        int gn = n0 + nOut, gk = k0 + kc;
        if (region == 0)      *(ushort4*)(Wt + gn * 512 + gk) = o;
        else if (region == 1) {
            int row = (gk < 512) ? (512 + gn) : (768 + gn);
            *(ushort4*)(Wt + row * 512 + (gk & 511)) = o;
        } else                *(ushort4*)(w2t + gn * 256 + gk) = o;
    }
}

// ---------------------------------------------------------------------------
// Kernel 1: MFMA GEMM C[1024][1024] = xb @ Wt^T. 2x2 tiles per wave
// (32 rows x 32 cols), grid (8,32) — round-3 config (best so far).
// ---------------------------------------------------------------------------
__global__ __launch_bounds__(256) void gemm_kernel(
    const __hip_bfloat16* __restrict__ xb, const __hip_bfloat16* __restrict__ Wt,
    const float* __restrict__ pp_b1, const float* __restrict__ cd_b1,
    __hip_bfloat16* __restrict__ hidg, float* __restrict__ Ug,
    float* __restrict__ Vg)
{
    const int t = threadIdx.x;
    const int wave = t >> 6, lane = t & 63;
    const int l = lane & 15, q = lane >> 4;
    const int m0 = blockIdx.y * 32;
    const int n0 = blockIdx.x * 128 + wave * 32;

    const __hip_bfloat16* a0p = xb + (m0 + l) * 512 + q * 8;
    const __hip_bfloat16* a1p = a0p + 16 * 512;
    const __hip_bfloat16* b0p = Wt + (n0 + l) * 512 + q * 8;
    const __hip_bfloat16* b1p = b0p + 16 * 512;

    f32x4 acc00 = {}, acc01 = {}, acc10 = {}, acc11 = {};
    #pragma unroll
    for (int ks = 0; ks < 16; ++ks) {
        bf16x8 a0 = *(const bf16x8*)(a0p + ks * 32);
        bf16x8 a1 = *(const bf16x8*)(a1p + ks * 32);
        bf16x8 b0 = *(const bf16x8*)(b0p + ks * 32);
        bf16x8 b1 = *(const bf16x8*)(b1p + ks * 32);
        acc00 = __builtin_amdgcn_mfma_f32_16x16x32_bf16(a0, b0, acc00, 0, 0, 0);
        acc01 = __builtin_amdgcn_mfma_f32_16x16x32_bf16(a0, b1, acc01, 0, 0, 0);
        acc10 = __builtin_amdgcn_mfma_f32_16x16x32_bf16(a1, b0, acc10, 0, 0, 0);
        acc11 = __builtin_amdgcn_mfma_f32_16x16x32_bf16(a1, b1, acc11, 0, 0, 0);
    }

    // C/D layout: col = l, row = q*4 + r
    const int c0 = n0 + l, c1 = n0 + 16 + l;
    #pragma unroll
    for (int mt = 0; mt < 2; ++mt) {
        const f32x4& A0 = mt ? acc10 : acc00;
        const f32x4& A1 = mt ? acc11 : acc01;
        if (n0 < 512) {
            float b0v = pp_b1[c0], b1v = pp_b1[c1];
            #pragma unroll
            for (int r = 0; r < 4; ++r) {
                int rg = m0 + mt * 16 + q * 4 + r;
                hidg[rg * 512 + c0] = __float2bfloat16(fmaxf(A0[r] + b0v, 0.f));
                hidg[rg * 512 + c1] = __float2bfloat16(fmaxf(A1[r] + b1v, 0.f));
            }
        } else if (n0 < 768) {
            float b0v = cd_b1[c0 - 512], b1v = cd_b1[c1 - 512];
            #pragma unroll
            for (int r = 0; r < 4; ++r) {
                int rg = m0 + mt * 16 + q * 4 + r;
                Ug[rg * 256 + (c0 - 512)] = A0[r] + b0v;
                Ug[rg * 256 + (c1 - 512)] = A1[r] + b1v;
            }
        } else {
            #pragma unroll
            for (int r = 0; r < 4; ++r) {
                int rg = m0 + mt * 16 + q * 4 + r;
                Vg[rg * 256 + (c0 - 768)] = A0[r];
                Vg[rg * 256 + (c1 - 768)] = A1[r];
            }
        }
    }
}

// ---------------------------------------------------------------------------
// Kernel 2: heads. One wave per row; 10 coalesced shuffle-reduce dots.
// ---------------------------------------------------------------------------
__global__ __launch_bounds__(256) void heads_kernel(
    const float* __restrict__ x, const __hip_bfloat16* __restrict__ hidg,
    const float* __restrict__ hw, const float* __restrict__ pp_b2,
    const float* __restrict__ vel_b, const float* __restrict__ frc_b,
    float* __restrict__ out)
{
    const int t = threadIdx.x, wave = t >> 6, lane = t & 63;
    const int row = blockIdx.x * 4 + wave;

    const float4* xr = (const float4*)(x + row * 512);
    float4 xa = xr[lane * 2], xc = xr[lane * 2 + 1];
    bf16x8 hb = *(const bf16x8*)(hidg + row * 512 + lane * 8);
    float hf[8];
    #pragma unroll
    for (int j = 0; j < 8; ++j) hf[j] = bf2f(hb[j]);

    #pragma unroll
    for (int h = 0; h < 10; ++h) {
        const float4* wr = (const float4*)(hw + h * 512);
        float4 wa = wr[lane * 2], wc = wr[lane * 2 + 1];
        float s;
        if (h < 4) {
            s = hf[0]*wa.x + hf[1]*wa.y + hf[2]*wa.z + hf[3]*wa.w
              + hf[4]*wc.x + hf[5]*wc.y + hf[6]*wc.z + hf[7]*wc.w;
        } else {
            s = xa.x*wa.x + xa.y*wa.y + xa.z*wa.z + xa.w*wa.w
              + xc.x*wc.x + xc.y*wc.y + xc.z*wc.z + xc.w*wc.w;
        }
        s += __shfl_xor(s, 1);  s += __shfl_xor(s, 2);
        s += __shfl_xor(s, 4);  s += __shfl_xor(s, 8);
        s += __shfl_xor(s, 16); s += __shfl_xor(s, 32);
        if (lane == 0) {
            if (h < 4) {
                float sg = sigmoidf_(s + pp_b2[h]);
                out[h * 1024 + row] = (h == 0) ? sg * 100.f : (h == 3) ? sg * 10.f : sg;
            } else if (h < 7) {
                out[4096 + row * 3 + (h - 4)] = s + vel_b[h - 4];
            } else {
                out[7168 + row * 3 + (h - 7)] = s + frc_b[h - 7];
            }
        }
    }
}

// ---------------------------------------------------------------------------
// Kernel 3: pair MLP v3. 16x16 (i,j) supertile = 256 pairs/block, grid
// (136, 4). Wave owns 4 i-rows x ALL 128 cols: A-frags built once, B-frags
// in registers, epilogue completes in-wave (no ps LDS, no 2nd barrier).
// m-tile mtg = one i (all lanes share U row mtg: LDS broadcast), A-row l = j.
// ---------------------------------------------------------------------------
__global__ __launch_bounds__(256) void pair_kernel(
    const float* __restrict__ Ug, const float* __restrict__ Vg,
    const __hip_bfloat16* __restrict__ w2t,  // [128][256] bf16
    const float* __restrict__ cd_b2, const float* __restrict__ cd_w3,
    const float* __restrict__ cd_b3, float* __restrict__ cm)
{
    const int b = blockIdx.y;
    const int tp = blockIdx.x;  // 0..135 -> (ti<=tj) over 16-row groups
    int ti = 0;
    while ((ti + 1) * (33 - (ti + 1)) / 2 <= tp) ++ti;
    const int tj = ti + (tp - ti * (33 - ti) / 2);

    __shared__ __align__(16) float Us[16][260];  // 16.6 KB, stride 260: 2-way free
    __shared__ __align__(16) float Vs[16][260];

    const int t = threadIdx.x;
    const int i0 = ti * 16, j0 = tj * 16;

    { // stage U (16 i-rows) and V (16 j-rows), 16 floats/thread each
        const int row = t >> 4, c0 = (t & 15) * 16;
        const float* Up = Ug + (b * 256 + i0 + row) * 256 + c0;
        const float* Vp = Vg + (b * 256 + j0 + row) * 256 + c0;
        #pragma unroll
        for (int i = 0; i < 4; ++i) {
            *(float4*)&Us[row][c0 + i * 4] = *(const float4*)(Up + i * 4);
            *(float4*)&Vs[row][c0 + i * 4] = *(const float4*)(Vp + i * 4);
        }
    }
    __syncthreads();

    const int wave = t >> 6, lane = t & 63;
    const int l = lane & 15, q = lane >> 4;

    f32x4 acc[4][8] = {};  // [mt][nt]
    const __hip_bfloat16* wB = w2t + l * 256 + q * 8;

    #pragma unroll
    for (int ks = 0; ks < 8; ++ks) {
        bf16x8 bfr[8];
        #pragma unroll
        for (int nt = 0; nt < 8; ++nt)
            bfr[nt] = *(const bf16x8*)(wB + nt * 16 * 256 + ks * 32);
        const int kk = ks * 32 + q * 8;
        #pragma unroll
        for (int mt = 0; mt < 4; ++mt) {
            const int mtg = wave * 4 + mt;   // i-row of this m-tile
            float4 u0 = *(const float4*)&Us[mtg][kk];      // broadcast
            float4 u1 = *(const float4*)&Us[mtg][kk + 4];
            float4 v0 = *(const float4*)&Vs[l][kk];        // 2-way, free
            float4 v1 = *(const float4*)&Vs[l][kk + 4];
            bf16x8 afr;
            afr[0] = f2bf(fmaxf(u0.x + v0.x, 0.f));
            afr[1] = f2bf(fmaxf(u0.y + v0.y, 0.f));
            afr[2] = f2bf(fmaxf(u0.z + v0.z, 0.f));
            afr[3] = f2bf(fmaxf(u0.w + v0.w, 0.f));
            afr[4] = f2bf(fmaxf(u1.x + v1.x, 0.f));
            afr[5] = f2bf(fmaxf(u1.y + v1.y, 0.f));
            afr[6] = f2bf(fmaxf(u1.z + v1.z, 0.f));
            afr[7] = f2bf(fmaxf(u1.w + v1.w, 0.f));
            #pragma unroll
            for (int nt = 0; nt < 8; ++nt)
                acc[mt][nt] = __builtin_amdgcn_mfma_f32_16x16x32_bf16(
                    afr, bfr[nt], acc[mt][nt], 0, 0, 0);
        }
    }

    // In-wave epilogue: g = relu(acc + b2), s = g . w3 over all 128 cols,
    // 16-lane shuffle reduce, direct symmetric scatter.
    float b2v[8], w3v[8];
    #pragma unroll
    for (int nt = 0; nt < 8; ++nt) {
        b2v[nt] = cd_b2[nt * 16 + l];
        w3v[nt] = cd_w3[nt * 16 + l];
    }
    const float b3 = cd_b3[0];
    float* base = cm + b * 65536;
    #pragma unroll
    for (int mt = 0; mt < 4; ++mt) {
        const int i = i0 + wave * 4 + mt;
        #pragma unroll
        for (int r = 0; r < 4; ++r) {
            // D layout: A-row (=j-local) = q*4 + r, col = nt*16 + l
            float s = 0.f;
            #pragma unroll
            for (int nt = 0; nt < 8; ++nt)
                s += fmaxf(acc[mt][nt][r] + b2v[nt], 0.f) * w3v[nt];
            s += __shfl_xor(s, 1);
            s += __shfl_xor(s, 2);
            s += __shfl_xor(s, 4);
            s += __shfl_xor(s, 8);
            if (l == 0) {
                const int j = j0 + q * 4 + r;
                float prob = sigmoidf_(s + b3);
                if (i < j) {
                    base[i * 256 + j] = prob;
                    base[j * 256 + i] = prob;
                } else if (i == j) {
                    base[i * 256 + i] = 0.0f;
                }
            }
        }
    }
}

// ---------------------------------------------------------------------------
extern "C" void kernel_launch(void* const* d_in, const int* in_sizes, int n_in,
                              void* d_out, int out_size, void* d_ws, size_t ws_size,
                              hipStream_t stream) {
    const float* x     = (const float*)d_in[0];
    const float* pp_w1 = (const float*)d_in[1];
    const float* pp_b1 = (const float*)d_in[2];
    const float* pp_w2 = (const float*)d_in[3];
    const float* pp_b2 = (const float*)d_in[4];
    const float* cd_w1 = (const float*)d_in[5];
    const float* cd_b1 = (const float*)d_in[6];
    const float* cd_w2 = (const float*)d_in[7];
    const float* cd_b2 = (const float*)d_in[8];
    const float* cd_w3 = (const float*)d_in[9];
    const float* cd_b3 = (const float*)d_in[10];
    const float* vel_w = (const float*)d_in[11];
    const float* vel_b = (const float*)d_in[12];
    const float* frc_w = (const float*)d_in[13];
    const float* frc_b = (const float*)d_in[14];

    float* out = (float*)d_out;
    // ws: Ug 1MB | Vg 1MB | xb 1MB | Wt 1MB | hidg 1MB | w2t 64KB | hw 20KB
    float* Ug = (float*)d_ws;
    float* Vg = Ug + 262144;
    __hip_bfloat16* xb   = (__hip_bfloat16*)(Vg + 262144);
    __hip_bfloat16* Wt   = xb + 524288;
    __hip_bfloat16* hidg = Wt + 524288;
    __hip_bfloat16* w2t  = hidg + 524288;
    float* hw = (float*)(w2t + 32768);

    convert_kernel<<<dim3(393), dim3(256), 0, stream>>>(
        x, pp_w1, cd_w1, cd_w2, pp_w2, vel_w, frc_w, xb, Wt, w2t, hw);
    gemm_kernel<<<dim3(8, 32), dim3(256), 0, stream>>>(
        xb, Wt, pp_b1, cd_b1, hidg, Ug, Vg);
    heads_kernel<<<dim3(256), dim3(256), 0, stream>>>(
        x, hidg, hw, pp_b2, vel_b, frc_b, out);
    pair_kernel<<<dim3(136, 4), dim3(256), 0, stream>>>(
        Ug, Vg, w2t, cd_b2, cd_w3, cd_b3, out + 10240);
}

// Round 6
// 140.802 us; speedup vs baseline: 1.1068x; 1.0246x over previous
//
#include <hip/hip_runtime.h>
#include <hip/hip_bf16.h>

typedef __attribute__((ext_vector_type(8))) short bf16x8;
typedef __attribute__((ext_vector_type(4))) float f32x4;

__device__ __forceinline__ float sigmoidf_(float v) {
    return 1.0f / (1.0f + __expf(-v));
}
__device__ __forceinline__ short f2bf(float f) {
    union { __hip_bfloat16 h; short s; } cv;
    cv.h = __float2bfloat16(f);
    return cv.s;
}
__device__ __forceinline__ float bf2f(short s) {
    union { float f; unsigned u; } cv;
    cv.u = ((unsigned)(unsigned short)s) << 16;
    return cv.f;
}

// ---------------------------------------------------------------------------
// Kernel 0: conversions, all coalesced. (unchanged)
// ---------------------------------------------------------------------------
__global__ __launch_bounds__(256) void convert_kernel(
    const float* __restrict__ x, const float* __restrict__ pp_w1,
    const float* __restrict__ cd_w1, const float* __restrict__ cd_w2,
    const float* __restrict__ pp_w2, const float* __restrict__ vel_w,
    const float* __restrict__ frc_w,
    __hip_bfloat16* __restrict__ xb, __hip_bfloat16* __restrict__ Wt,
    __hip_bfloat16* __restrict__ w2t, float* __restrict__ hw)
{
    __shared__ float ts[64][65];
    const int b = blockIdx.x, t = threadIdx.x;

    if (b < 256) {  // xb cast
        int base = b * 2048 + t * 8;
        float4 a = *(const float4*)(x + base);
        float4 c = *(const float4*)(x + base + 4);
        bf16x8 o;
        o[0] = f2bf(a.x); o[1] = f2bf(a.y); o[2] = f2bf(a.z); o[3] = f2bf(a.w);
        o[4] = f2bf(c.x); o[5] = f2bf(c.y); o[6] = f2bf(c.z); o[7] = f2bf(c.w);
        *(bf16x8*)(xb + base) = o;
        return;
    }
    if (b == 392) {  // hw pack
        for (int e = t; e < 5120; e += 256) {
            int h = e >> 9, k = e & 511;
            float v = (h < 4) ? pp_w2[k * 128 + h]
                    : (h < 7) ? vel_w[k * 3 + (h - 4)]
                              : frc_w[k * 3 + (h - 7)];
            hw[e] = v;
        }
        return;
    }

    const float* src; int ss, k0, n0, region;
    if (b < 320)      { int i = b - 256; src = pp_w1; ss = 512; k0 = (i >> 3) * 64; n0 = (i & 7) * 64; region = 0; }
    else if (b < 384) { int i = b - 320; src = cd_w1; ss = 256; k0 = (i >> 2) * 64; n0 = (i & 3) * 64; region = 1; }
    else              { int i = b - 384; src = cd_w2; ss = 128; k0 = (i >> 1) * 64; n0 = (i & 1) * 64; region = 2; }

    #pragma unroll
    for (int i = 0; i < 4; ++i) {
        int r = (t >> 4) + i * 16, c4 = (t & 15) * 4;
        *(float4*)&ts[r][c4] = *(const float4*)(src + (k0 + r) * ss + n0 + c4);
    }
    __syncthreads();
    #pragma unroll
    for (int i = 0; i < 4; ++i) {
        int nOut = (t >> 4) + i * 16, kc = (t & 15) * 4;
        ushort4 o;
        o.x = (unsigned short)f2bf(ts[kc + 0][nOut]);
        o.y = (unsigned short)f2bf(ts[kc + 1][nOut]);
        o.z = (unsigned short)f2bf(ts[kc + 2][nOut]);
        o.w = (unsigned short)f2bf(ts[kc + 3][nOut]);
        int gn = n0 + nOut, gk = k0 + kc;
        if (region == 0)      *(ushort4*)(Wt + gn * 512 + gk) = o;
        else if (region == 1) {
            int row = (gk < 512) ? (512 + gn) : (768 + gn);
            *(ushort4*)(Wt + row * 512 + (gk & 511)) = o;
        } else                *(ushort4*)(w2t + gn * 256 + gk) = o;
    }
}

// ---------------------------------------------------------------------------
// Kernel 1: MFMA GEMM C[1024][1024] = xb @ Wt^T. 2x2 tiles/wave, grid (8,32).
// (unchanged — best config so far)
// ---------------------------------------------------------------------------
__global__ __launch_bounds__(256) void gemm_kernel(
    const __hip_bfloat16* __restrict__ xb, const __hip_bfloat16* __restrict__ Wt,
    const float* __restrict__ pp_b1, const float* __restrict__ cd_b1,
    __hip_bfloat16* __restrict__ hidg, float* __restrict__ Ug,
    float* __restrict__ Vg)
{
    const int t = threadIdx.x;
    const int wave = t >> 6, lane = t & 63;
    const int l = lane & 15, q = lane >> 4;
    const int m0 = blockIdx.y * 32;
    const int n0 = blockIdx.x * 128 + wave * 32;

    const __hip_bfloat16* a0p = xb + (m0 + l) * 512 + q * 8;
    const __hip_bfloat16* a1p = a0p + 16 * 512;
    const __hip_bfloat16* b0p = Wt + (n0 + l) * 512 + q * 8;
    const __hip_bfloat16* b1p = b0p + 16 * 512;

    f32x4 acc00 = {}, acc01 = {}, acc10 = {}, acc11 = {};
    #pragma unroll
    for (int ks = 0; ks < 16; ++ks) {
        bf16x8 a0 = *(const bf16x8*)(a0p + ks * 32);
        bf16x8 a1 = *(const bf16x8*)(a1p + ks * 32);
        bf16x8 b0 = *(const bf16x8*)(b0p + ks * 32);
        bf16x8 b1 = *(const bf16x8*)(b1p + ks * 32);
        acc00 = __builtin_amdgcn_mfma_f32_16x16x32_bf16(a0, b0, acc00, 0, 0, 0);
        acc01 = __builtin_amdgcn_mfma_f32_16x16x32_bf16(a0, b1, acc01, 0, 0, 0);
        acc10 = __builtin_amdgcn_mfma_f32_16x16x32_bf16(a1, b0, acc10, 0, 0, 0);
        acc11 = __builtin_amdgcn_mfma_f32_16x16x32_bf16(a1, b1, acc11, 0, 0, 0);
    }

    const int c0 = n0 + l, c1 = n0 + 16 + l;
    #pragma unroll
    for (int mt = 0; mt < 2; ++mt) {
        const f32x4& A0 = mt ? acc10 : acc00;
        const f32x4& A1 = mt ? acc11 : acc01;
        if (n0 < 512) {
            float b0v = pp_b1[c0], b1v = pp_b1[c1];
            #pragma unroll
            for (int r = 0; r < 4; ++r) {
                int rg = m0 + mt * 16 + q * 4 + r;
                hidg[rg * 512 + c0] = __float2bfloat16(fmaxf(A0[r] + b0v, 0.f));
                hidg[rg * 512 + c1] = __float2bfloat16(fmaxf(A1[r] + b1v, 0.f));
            }
        } else if (n0 < 768) {
            float b0v = cd_b1[c0 - 512], b1v = cd_b1[c1 - 512];
            #pragma unroll
            for (int r = 0; r < 4; ++r) {
                int rg = m0 + mt * 16 + q * 4 + r;
                Ug[rg * 256 + (c0 - 512)] = A0[r] + b0v;
                Ug[rg * 256 + (c1 - 512)] = A1[r] + b1v;
            }
        } else {
            #pragma unroll
            for (int r = 0; r < 4; ++r) {
                int rg = m0 + mt * 16 + q * 4 + r;
                Vg[rg * 256 + (c0 - 768)] = A0[r];
                Vg[rg * 256 + (c1 - 768)] = A1[r];
            }
        }
    }
}

// ---------------------------------------------------------------------------
// Kernel 2: heads. (unchanged)
// ---------------------------------------------------------------------------
__global__ __launch_bounds__(256) void heads_kernel(
    const float* __restrict__ x, const __hip_bfloat16* __restrict__ hidg,
    const float* __restrict__ hw, const float* __restrict__ pp_b2,
    const float* __restrict__ vel_b, const float* __restrict__ frc_b,
    float* __restrict__ out)
{
    const int t = threadIdx.x, wave = t >> 6, lane = t & 63;
    const int row = blockIdx.x * 4 + wave;

    const float4* xr = (const float4*)(x + row * 512);
    float4 xa = xr[lane * 2], xc = xr[lane * 2 + 1];
    bf16x8 hb = *(const bf16x8*)(hidg + row * 512 + lane * 8);
    float hf[8];
    #pragma unroll
    for (int j = 0; j < 8; ++j) hf[j] = bf2f(hb[j]);

    #pragma unroll
    for (int h = 0; h < 10; ++h) {
        const float4* wr = (const float4*)(hw + h * 512);
        float4 wa = wr[lane * 2], wc = wr[lane * 2 + 1];
        float s;
        if (h < 4) {
            s = hf[0]*wa.x + hf[1]*wa.y + hf[2]*wa.z + hf[3]*wa.w
              + hf[4]*wc.x + hf[5]*wc.y + hf[6]*wc.z + hf[7]*wc.w;
        } else {
            s = xa.x*wa.x + xa.y*wa.y + xa.z*wa.z + xa.w*wa.w
              + xc.x*wc.x + xc.y*wc.y + xc.z*wc.z + xc.w*wc.w;
        }
        s += __shfl_xor(s, 1);  s += __shfl_xor(s, 2);
        s += __shfl_xor(s, 4);  s += __shfl_xor(s, 8);
        s += __shfl_xor(s, 16); s += __shfl_xor(s, 32);
        if (lane == 0) {
            if (h < 4) {
                float sg = sigmoidf_(s + pp_b2[h]);
                out[h * 1024 + row] = (h == 0) ? sg * 100.f : (h == 3) ? sg * 10.f : sg;
            } else if (h < 7) {
                out[4096 + row * 3 + (h - 4)] = s + vel_b[h - 4];
            } else {
                out[7168 + row * 3 + (h - 7)] = s + frc_b[h - 7];
            }
        }
    }
}

// ---------------------------------------------------------------------------
// Kernel 3: pair MLP v5. Wave-independent workers; w2t staged once into LDS
// in granule-transposed layout w2s[g=k/8][n] (conflict-free b128 B-frag
// reads); A-frags built in regs from global U/V; acc[8]=32 VGPR; one barrier.
// Block = 512 thr = 8 waves = 4 quadrants x 2 batches of one 8x8 tile.
// Grid (528 tiles, 2 batch-pairs).
// ---------------------------------------------------------------------------
__global__ __launch_bounds__(512, 4) void pair_kernel(
    const float* __restrict__ Ug, const float* __restrict__ Vg,
    const __hip_bfloat16* __restrict__ w2t,  // [128][256] bf16 (n-major)
    const float* __restrict__ cd_b2, const float* __restrict__ cd_w3,
    const float* __restrict__ cd_b3, float* __restrict__ cm)
{
    __shared__ __align__(16) short w2s[32 * 128 * 8];  // 64 KB exactly

    const int tp = blockIdx.x;   // 0..527 -> (ti<=tj) over 8-row groups (32)
    const int bz = blockIdx.y;   // 0..1
    int ti = 0;
    while ((ti + 1) * (65 - (ti + 1)) / 2 <= tp) ++ti;
    const int tj = ti + (tp - ti * (65 - ti) / 2);
    const int i0 = ti * 8, j0 = tj * 8;

    const int t = threadIdx.x;

    { // stage w2t -> w2s[g][n]: e -> n = e>>5, g = e&31 (coalesced global read)
        #pragma unroll
        for (int it = 0; it < 8; ++it) {
            int e = it * 512 + t;
            int n = e >> 5, g = e & 31;
            uint4 d = *(const uint4*)(w2t + n * 256 + g * 8);
            *(uint4*)(w2s + (g * 128 + n) * 8) = d;
        }
    }
    __syncthreads();

    const int w = t >> 6, lane = t & 63;
    const int qd = w & 3;            // quadrant: slots qd*16 .. qd*16+15
    const int b = bz * 2 + (w >> 2); // batch
    const int l = lane & 15, q = lane >> 4;

    const int pb = qd * 16 + l;      // slot whose h-row this lane builds
    const float* Up = Ug + (b * 256 + i0 + (pb >> 3)) * 256;
    const float* Vp = Vg + (b * 256 + j0 + (pb & 7)) * 256;

    f32x4 acc[8] = {};
    #pragma unroll
    for (int ks = 0; ks < 8; ++ks) {
        const int kk = ks * 32 + q * 8;
        float4 u0 = *(const float4*)(Up + kk);
        float4 u1 = *(const float4*)(Up + kk + 4);
        float4 v0 = *(const float4*)(Vp + kk);
        float4 v1 = *(const float4*)(Vp + kk + 4);
        bf16x8 afr;
        afr[0] = f2bf(fmaxf(u0.x + v0.x, 0.f));
        afr[1] = f2bf(fmaxf(u0.y + v0.y, 0.f));
        afr[2] = f2bf(fmaxf(u0.z + v0.z, 0.f));
        afr[3] = f2bf(fmaxf(u0.w + v0.w, 0.f));
        afr[4] = f2bf(fmaxf(u1.x + v1.x, 0.f));
        afr[5] = f2bf(fmaxf(u1.y + v1.y, 0.f));
        afr[6] = f2bf(fmaxf(u1.z + v1.z, 0.f));
        afr[7] = f2bf(fmaxf(u1.w + v1.w, 0.f));
        const short* wg = w2s + (ks * 4 + q) * 128 * 8;  // granule block
        #pragma unroll
        for (int nt = 0; nt < 8; ++nt) {
            bf16x8 bfr = *(const bf16x8*)(wg + (nt * 16 + l) * 8);
            acc[nt] = __builtin_amdgcn_mfma_f32_16x16x32_bf16(afr, bfr, acc[nt], 0, 0, 0);
        }
    }

    // In-wave epilogue: layer 3 over all 128 cols + 16-lane reduce + scatter.
    float b2v[8], w3v[8];
    #pragma unroll
    for (int nt = 0; nt < 8; ++nt) {
        b2v[nt] = cd_b2[nt * 16 + l];
        w3v[nt] = cd_w3[nt * 16 + l];
    }
    const float b3 = cd_b3[0];
    float* base = cm + b * 65536;
    #pragma unroll
    for (int r = 0; r < 4; ++r) {
        // D layout: slot (M) = q*4 + r within quadrant, col (N) = nt*16 + l
        float s = 0.f;
        #pragma unroll
        for (int nt = 0; nt < 8; ++nt)
            s += fmaxf(acc[nt][r] + b2v[nt], 0.f) * w3v[nt];
        s += __shfl_xor(s, 1);
        s += __shfl_xor(s, 2);
        s += __shfl_xor(s, 4);
        s += __shfl_xor(s, 8);
        if (l == 0) {
            const int p = qd * 16 + q * 4 + r;
            const int i = i0 + (p >> 3), j = j0 + (p & 7);
            float prob = sigmoidf_(s + b3);
            if (i < j) {
                base[i * 256 + j] = prob;
                base[j * 256 + i] = prob;
            } else if (i == j) {
                base[i * 256 + i] = 0.0f;
            }
        }
    }
}

// ---------------------------------------------------------------------------
extern "C" void kernel_launch(void* const* d_in, const int* in_sizes, int n_in,
                              void* d_out, int out_size, void* d_ws, size_t ws_size,
                              hipStream_t stream) {
    const float* x     = (const float*)d_in[0];
    const float* pp_w1 = (const float*)d_in[1];
    const float* pp_b1 = (const float*)d_in[2];
    const float* pp_w2 = (const float*)d_in[3];
    const float* pp_b2 = (const float*)d_in[4];
    const float* cd_w1 = (const float*)d_in[5];
    const float* cd_b1 = (const float*)d_in[6];
    const float* cd_w2 = (const float*)d_in[7];
    const float* cd_b2 = (const float*)d_in[8];
    const float* cd_w3 = (const float*)d_in[9];
    const float* cd_b3 = (const float*)d_in[10];
    const float* vel_w = (const float*)d_in[11];
    const float* vel_b = (const float*)d_in[12];
    const float* frc_w = (const float*)d_in[13];
    const float* frc_b = (const float*)d_in[14];

    float* out = (float*)d_out;
    // ws: Ug 1MB | Vg 1MB | xb 1MB | Wt 1MB | hidg 1MB | w2t 64KB | hw 20KB
    float* Ug = (float*)d_ws;
    float* Vg = Ug + 262144;
    __hip_bfloat16* xb   = (__hip_bfloat16*)(Vg + 262144);
    __hip_bfloat16* Wt   = xb + 524288;
    __hip_bfloat16* hidg = Wt + 524288;
    __hip_bfloat16* w2t  = hidg + 524288;
    float* hw = (float*)(w2t + 32768);

    convert_kernel<<<dim3(393), dim3(256), 0, stream>>>(
        x, pp_w1, cd_w1, cd_w2, pp_w2, vel_w, frc_w, xb, Wt, w2t, hw);
    gemm_kernel<<<dim3(8, 32), dim3(256), 0, stream>>>(
        xb, Wt, pp_b1, cd_b1, hidg, Ug, Vg);
    heads_kernel<<<dim3(256), dim3(256), 0, stream>>>(
        x, hidg, hw, pp_b2, vel_b, frc_b, out);
    pair_kernel<<<dim3(528, 2), dim3(512), 0, stream>>>(
        Ug, Vg, w2t, cd_b2, cd_w3, cd_b3, out + 10240);
}